// Round 1
// baseline (107.023 us; speedup 1.0000x reference)
//
#include <hip/hip_runtime.h>
#include <cmath>

#define NB 32
#define HH 14
#define WW 14
#define CC 32
#define KK 64
#define KS5 5
#define OH 10
#define OW 10
#define PP 100            // OH*OW
#define MM 800            // KS5*KS5*CC
#define HWC (HH*WW*CC)    // 6272
#define MU_OUT_SZ (NB*PP*KK)  // 204800
#define PADC 33

// Kernel A: conv for mu_out  +  diag_vals = v1 + sp*tr  (into workspace)
__global__ __launch_bounds__(256) void convA(
    const float* __restrict__ mu_in,
    const float* __restrict__ Sigma_in,
    const float* __restrict__ w_mu,
    const float* __restrict__ w_sigma,
    float* __restrict__ mu_out,
    float* __restrict__ dv_ws) {
  __shared__ float mu_lds[HWC];
  __shared__ float sd_lds[HWC];
  const int b = blockIdx.y;
  const int tile = blockIdx.x;          // 0..24
  const int t = threadIdx.x;
  const int k = t & 63;
  const int pg = t >> 6;                // 0..3
  const int p = tile * 4 + pg;          // 0..99

  // stage mu_in[b] and diag(Sigma_in)[b] into LDS (float4)
  const float4* mu4 = (const float4*)(mu_in + (size_t)b * HWC);
  for (int f = t; f < HWC / 4; f += 256) {
    ((float4*)mu_lds)[f] = mu4[f];
    const int n  = f >> 3;              // (f*4)/32
    const int c4 = (f & 7) << 2;
    const float4 s = *(const float4*)(Sigma_in +
        ((size_t)(b * 196 + n) * 196 + n) * 32 + c4);
    ((float4*)sd_lds)[f] = s;
  }
  __syncthreads();

  const int ph = p / OW, pw = p % OW;
  float accm = 0.f, accv = 0.f, tr = 0.f;
  for (int ij = 0; ij < 25; ++ij) {
    const int i = ij / 5, j = ij % 5;
    const int xbase = ((ph + i) * WW + (pw + j)) * CC;
    const int wbase = ij * CC * KK + k;
#pragma unroll
    for (int c = 0; c < CC; ++c) {
      const float wv = w_mu[wbase + c * KK];
      const float xm = mu_lds[xbase + c];
      const float xs = sd_lds[xbase + c];
      accm = fmaf(xm, wv, accm);
      accv = fmaf(xs, wv * wv, accv);
      tr  += xs;
    }
  }
  const float sp = log1pf(expf(w_sigma[k]));
  const size_t o = ((size_t)b * PP + p) * KK + k;
  mu_out[o] = accm;
  dv_ws[o]  = accv + sp * tr;
}

// Kernel C: per (b,p): G-row + write Sigma_out[b,p,:,:]
__global__ __launch_bounds__(256) void sigmaC(
    const float* __restrict__ mu_in,
    const float* __restrict__ w_sigma,
    const float* __restrict__ dv_ws,
    float* __restrict__ out) {
  __shared__ float mu_lds[HH * WW * PADC];   // padded stride 33 per (h,w)
  __shared__ float g_lds[2][PP];
  const int b = blockIdx.y;
  const int p = blockIdx.x;
  const int t = threadIdx.x;

  // stage mu_in[b] with channel padding (conflict-free q-reads later)
  const float4* mu4 = (const float4*)(mu_in + (size_t)b * HWC);
  for (int f = t; f < HWC / 4; f += 256) {
    const float4 v = mu4[f];
    const int hw = f >> 3;
    const int c  = (f & 7) << 2;
    float* d = &mu_lds[hw * PADC + c];
    d[0] = v.x; d[1] = v.y; d[2] = v.z; d[3] = v.w;
  }
  __syncthreads();

  const int ph = p / OW, pw = p % OW;
  if (t < 200) {
    const int q = t % 100;
    const int part = t / 100;          // 0 or 1
    const int qh = q / OW, qw = q % OW;
    const int ij0 = part ? 13 : 0;
    const int ij1 = part ? 25 : 13;
    float acc = 0.f;
    for (int ij = ij0; ij < ij1; ++ij) {
      const int i = ij / 5, j = ij % 5;
      const float* pprow = &mu_lds[((ph + i) * WW + (pw + j)) * PADC];
      const float* qqrow = &mu_lds[((qh + i) * WW + (qw + j)) * PADC];
#pragma unroll
      for (int c = 0; c < CC; ++c)
        acc = fmaf(pprow[c], qqrow[c], acc);
    }
    g_lds[part][q] = acc;
  }
  __syncthreads();

  // write phase: float4 over [q,k]; k4 = first k in this thread's float4
  const int k4 = (t * 4) & 63;
  float4 sp4, dv4;
  {
    const float4 wsv = *(const float4*)(w_sigma + k4);
    sp4.x = log1pf(expf(wsv.x));
    sp4.y = log1pf(expf(wsv.y));
    sp4.z = log1pf(expf(wsv.z));
    sp4.w = log1pf(expf(wsv.w));
    dv4 = *(const float4*)(dv_ws + ((size_t)b * PP + p) * KK + k4);
  }
  float* sig = out + MU_OUT_SZ + (size_t)(b * PP + p) * PP * KK;
  for (int l4 = t; l4 < PP * KK / 4; l4 += 256) {   // 1600 float4s
    const int q = l4 >> 4;                          // (l4*4)/64
    const float g = g_lds[0][q] + g_lds[1][q];
    float4 v;
    v.x = sp4.x * g; v.y = sp4.y * g; v.z = sp4.z * g; v.w = sp4.w * g;
    if (q == p) { v.x += dv4.x; v.y += dv4.y; v.z += dv4.z; v.w += dv4.w; }
    v.x = isfinite(v.x) ? v.x : 0.f;
    v.y = isfinite(v.y) ? v.y : 0.f;
    v.z = isfinite(v.z) ? v.z : 0.f;
    v.w = isfinite(v.w) ? v.w : 0.f;
    if (q == k4)     v.x = fabsf(v.x);
    if (q == k4 + 1) v.y = fabsf(v.y);
    if (q == k4 + 2) v.z = fabsf(v.z);
    if (q == k4 + 3) v.w = fabsf(v.w);
    *(float4*)(sig + (size_t)l4 * 4) = v;
  }
}

extern "C" void kernel_launch(void* const* d_in, const int* in_sizes, int n_in,
                              void* d_out, int out_size, void* d_ws, size_t ws_size,
                              hipStream_t stream) {
  const float* mu_in    = (const float*)d_in[0];
  const float* Sigma_in = (const float*)d_in[1];
  const float* w_mu     = (const float*)d_in[2];
  const float* w_sigma  = (const float*)d_in[3];
  float* out = (float*)d_out;
  float* dv  = (float*)d_ws;   // needs NB*PP*KK*4 = 819200 bytes

  convA<<<dim3(25, NB), 256, 0, stream>>>(mu_in, Sigma_in, w_mu, w_sigma, out, dv);
  sigmaC<<<dim3(PP, NB), 256, 0, stream>>>(mu_in, w_sigma, dv, out);
}

// Round 2
// 40.212 us; speedup vs baseline: 2.6615x; 2.6615x over previous
//
#include <hip/hip_runtime.h>
#include <cmath>

typedef __attribute__((ext_vector_type(8))) short short8;
typedef __attribute__((ext_vector_type(4))) float f32x4;

#define NB 32
#define PP 100
#define KK 64
#define MU_OUT_SZ (NB*PP*KK)   // 204800

// ws byte offsets
#define WS_MU   0              // bf16 [32][196][32]  = 401408 B
#define WS_SD   401408         // bf16 [32][196][32]  = 401408 B
#define WS_WF   802816         // bf16 frags [25][2][4][64][8] = 204800 B
#define WS_G    1007616        // f32 [32][100][100]  = 1280000 B
#define WS_DV   2287616        // f32 [32][100][64]   = 819200 B

__device__ inline unsigned short f2bf(float f) {
  unsigned u = __builtin_bit_cast(unsigned, f);
  u += 0x7fffu + ((u >> 16) & 1u);
  return (unsigned short)(u >> 16);
}

// ---------------- prep: bf16 conversions + W fragment packing ----------------
__global__ __launch_bounds__(256) void prep(
    const float* __restrict__ mu_in, const float* __restrict__ Sigma_in,
    const float* __restrict__ w_mu, const float* __restrict__ w_sigma,
    unsigned char* __restrict__ ws) {
  const int gid = blockIdx.x, t = threadIdx.x;
  unsigned short* mu_b = (unsigned short*)(ws + WS_MU);
  unsigned short* sd_b = (unsigned short*)(ws + WS_SD);
  unsigned short* wf   = (unsigned short*)(ws + WS_WF);
  if (gid < 98) {
    const int e = gid * 256 + t;        // 0..25087
    const int f = e * 8;                // element index into [32][196][32]
    const int b = f / 6272, rem = f % 6272;
    const int n = rem / 32, c0 = rem % 32;
    const float4 m0 = *(const float4*)(mu_in + f);
    const float4 m1 = *(const float4*)(mu_in + f + 4);
    const size_t sb = ((size_t)(b * 196 + n) * 196 + n) * 32 + c0;
    const float4 s0 = *(const float4*)(Sigma_in + sb);
    const float4 s1 = *(const float4*)(Sigma_in + sb + 4);
    uint4 pm, ps;
    pm.x = f2bf(m0.x) | ((unsigned)f2bf(m0.y) << 16);
    pm.y = f2bf(m0.z) | ((unsigned)f2bf(m0.w) << 16);
    pm.z = f2bf(m1.x) | ((unsigned)f2bf(m1.y) << 16);
    pm.w = f2bf(m1.z) | ((unsigned)f2bf(m1.w) << 16);
    ps.x = f2bf(s0.x) | ((unsigned)f2bf(s0.y) << 16);
    ps.y = f2bf(s0.z) | ((unsigned)f2bf(s0.w) << 16);
    ps.z = f2bf(s1.x) | ((unsigned)f2bf(s1.y) << 16);
    ps.w = f2bf(s1.z) | ((unsigned)f2bf(s1.w) << 16);
    *(uint4*)(mu_b + f) = pm;
    *(uint4*)(sd_b + f) = ps;
  } else {
    const int wid = (gid - 98) * 256 + t;   // 0..12799
    const int kind = wid >= 6400 ? 1 : 0;   // 0: W, 1: W^2 + sp
    const int fid = kind ? wid - 6400 : wid;
    const int ij = fid >> 8;                // 0..24
    const int rest = fid & 255;
    const int n = rest >> 6, l = rest & 63;
    const int col = n * 16 + (l & 15);      // k (output channel)
    const int m0 = ij * 32 + (l >> 4) * 8;  // m row base
    const float sp = log1pf(expf(w_sigma[col]));
    unsigned short v[8];
#pragma unroll
    for (int i = 0; i < 8; ++i) {
      float wv = w_mu[(m0 + i) * 64 + col];
      float x = kind ? (wv * wv + sp) : wv;
      v[i] = f2bf(x);
    }
    uint4 pk;
    pk.x = v[0] | ((unsigned)v[1] << 16);
    pk.y = v[2] | ((unsigned)v[3] << 16);
    pk.z = v[4] | ((unsigned)v[5] << 16);
    pk.w = v[6] | ((unsigned)v[7] << 16);
    *(uint4*)(wf + ((size_t)((ij * 8 + kind * 4 + n) * 64 + l)) * 8) = pk;
  }
}

// ---------------- gemmM: G = Mp*Mp^T, mu_out = Mp*W, dv = Sp*W2s ----------------
__global__ __launch_bounds__(128) void gemmM(
    unsigned char* __restrict__ ws, float* __restrict__ out) {
  __shared__ uint4 mu_sh4[784];
  __shared__ uint4 sd_sh4[784];
  const int b = blockIdx.y, r = blockIdx.x;   // r = row tile 0..6
  const int t = threadIdx.x, l = t & 63, w = t >> 6;
  const uint4* mu_g = (const uint4*)((const unsigned short*)(ws + WS_MU) + b * 6272);
  const uint4* sd_g = (const uint4*)((const unsigned short*)(ws + WS_SD) + b * 6272);
  for (int f = t; f < 784; f += 128) {
    mu_sh4[f] = mu_g[f];
    sd_sh4[f] = sd_g[f];
  }
  __syncthreads();
  const unsigned short* mu_sh = (const unsigned short*)mu_sh4;
  const unsigned short* sd_sh = (const unsigned short*)sd_sh4;
  const int g16 = (l >> 4) * 8;
  const int laneP = l & 15;

  if (w == 0) {
    // G row-tile r: 7 column tiles
    int base[7];
#pragma unroll
    for (int c = 0; c < 7; ++c) {
      int p = c * 16 + laneP; if (p > 99) p = 99;
      base[c] = ((p / 10) * 14 + (p % 10)) * 32 + g16;
    }
    int pA = r * 16 + laneP; if (pA > 99) pA = 99;
    const int baseA = ((pA / 10) * 14 + (pA % 10)) * 32 + g16;
    f32x4 acc[7] = {};
    for (int ij = 0; ij < 25; ++ij) {
      const int off = ((ij / 5) * 14 + (ij % 5)) * 32;
      short8 fA = *(const short8*)(mu_sh + baseA + off);
      short8 fr[7];
#pragma unroll
      for (int c = 0; c < 7; ++c) fr[c] = *(const short8*)(mu_sh + base[c] + off);
#pragma unroll
      for (int c = 0; c < 7; ++c)
        acc[c] = __builtin_amdgcn_mfma_f32_16x16x32_bf16(fA, fr[c], acc[c], 0, 0, 0);
    }
    float* Gp = (float*)(ws + WS_G) + (size_t)b * 10000;
    const int row0 = r * 16 + (l >> 4) * 4;
#pragma unroll
    for (int c = 0; c < 7; ++c) {
      int col = c * 16 + laneP;
      if (col < 100) {
#pragma unroll
        for (int j = 0; j < 4; ++j) {
          int row = row0 + j;
          if (row < 100) Gp[row * 100 + col] = acc[c][j];
        }
      }
    }
  } else {
    // mu_out and dv for row tile r
    int pA = r * 16 + laneP; if (pA > 99) pA = 99;
    const int baseA = ((pA / 10) * 14 + (pA % 10)) * 32 + g16;
    const unsigned short* wfp = (const unsigned short*)(ws + WS_WF);
    f32x4 am[4] = {}, ad[4] = {};
    for (int ij = 0; ij < 25; ++ij) {
      const int off = ((ij / 5) * 14 + (ij % 5)) * 32;
      short8 fa = *(const short8*)(mu_sh + baseA + off);
      short8 fs = *(const short8*)(sd_sh + baseA + off);
#pragma unroll
      for (int n = 0; n < 4; ++n) {
        short8 bw = *(const short8*)(wfp + (size_t)((ij * 8 + n) * 64 + l) * 8);
        short8 b2 = *(const short8*)(wfp + (size_t)((ij * 8 + 4 + n) * 64 + l) * 8);
        am[n] = __builtin_amdgcn_mfma_f32_16x16x32_bf16(fa, bw, am[n], 0, 0, 0);
        ad[n] = __builtin_amdgcn_mfma_f32_16x16x32_bf16(fs, b2, ad[n], 0, 0, 0);
      }
    }
    const int row0 = r * 16 + (l >> 4) * 4;
    float* dvp = (float*)(ws + WS_DV) + (size_t)b * 6400;
    float* mo  = out + (size_t)b * 6400;
#pragma unroll
    for (int n = 0; n < 4; ++n) {
      int k = n * 16 + laneP;
#pragma unroll
      for (int j = 0; j < 4; ++j) {
        int p = row0 + j;
        if (p < 100) {
          mo[p * 64 + k]  = am[n][j];
          dvp[p * 64 + k] = ad[n][j];
        }
      }
    }
  }
}

// ---------------- writer: stream Sigma_out ----------------
__global__ __launch_bounds__(256) void writer(
    const unsigned char* __restrict__ ws, const float* __restrict__ w_sigma,
    float* __restrict__ out) {
  __shared__ float g_sh[100];
  const int b = blockIdx.y, p = blockIdx.x, t = threadIdx.x;
  const float* Gp = (const float*)(ws + WS_G) + (size_t)b * 10000 + p * 100;
  if (t < 25) *(float4*)(g_sh + t * 4) = *(const float4*)(Gp + t * 4);
  const int k4 = (t * 4) & 63;
  const float4 wsv = *(const float4*)(w_sigma + k4);
  float4 sp4;
  sp4.x = log1pf(expf(wsv.x));
  sp4.y = log1pf(expf(wsv.y));
  sp4.z = log1pf(expf(wsv.z));
  sp4.w = log1pf(expf(wsv.w));
  const float4 dv4 = *(const float4*)((const float*)(ws + WS_DV) + (size_t)b * 6400 + p * 64 + k4);
  __syncthreads();
  float* sig = out + MU_OUT_SZ + (size_t)(b * 100 + p) * 6400;
  for (int l4 = t; l4 < 1600; l4 += 256) {
    const int q = l4 >> 4;
    const float g = g_sh[q];
    float4 v;
    v.x = sp4.x * g; v.y = sp4.y * g; v.z = sp4.z * g; v.w = sp4.w * g;
    if (q == p) { v.x += dv4.x; v.y += dv4.y; v.z += dv4.z; v.w += dv4.w; }
    v.x = isfinite(v.x) ? v.x : 0.f;
    v.y = isfinite(v.y) ? v.y : 0.f;
    v.z = isfinite(v.z) ? v.z : 0.f;
    v.w = isfinite(v.w) ? v.w : 0.f;
    if (q == k4)     v.x = fabsf(v.x);
    if (q == k4 + 1) v.y = fabsf(v.y);
    if (q == k4 + 2) v.z = fabsf(v.z);
    if (q == k4 + 3) v.w = fabsf(v.w);
    *(float4*)(sig + (size_t)l4 * 4) = v;
  }
}

extern "C" void kernel_launch(void* const* d_in, const int* in_sizes, int n_in,
                              void* d_out, int out_size, void* d_ws, size_t ws_size,
                              hipStream_t stream) {
  const float* mu_in    = (const float*)d_in[0];
  const float* Sigma_in = (const float*)d_in[1];
  const float* w_mu     = (const float*)d_in[2];
  const float* w_sigma  = (const float*)d_in[3];
  float* out = (float*)d_out;
  unsigned char* ws = (unsigned char*)d_ws;

  prep<<<148, 256, 0, stream>>>(mu_in, Sigma_in, w_mu, w_sigma, ws);
  gemmM<<<dim3(7, NB), 128, 0, stream>>>(ws, out);
  writer<<<dim3(PP, NB), 256, 0, stream>>>(ws, w_sigma, out);
}

// Round 3
// 34.625 us; speedup vs baseline: 3.0909x; 1.1613x over previous
//
#include <hip/hip_runtime.h>
#include <cmath>

typedef __attribute__((ext_vector_type(8))) short short8;
typedef __attribute__((ext_vector_type(4))) float f32x4;

#define NB 32
#define PP 100
#define KK 64
#define MU_OUT_SZ (NB*PP*KK)   // 204800
#define LDAP 56                // shorts per (h,w) row in LDS (112 B padded)

__device__ inline unsigned short f2bf(float f) {
  unsigned u = __builtin_bit_cast(unsigned, f);
  u += 0x7fffu + ((u >> 16) & 1u);
  return (unsigned short)(u >> 16);
}

// ---------------- prepW: pack W and (W^2 + softplus) into MFMA B-frag order ----------------
__global__ __launch_bounds__(256) void prepW(
    const float* __restrict__ w_mu, const float* __restrict__ w_sigma,
    unsigned short* __restrict__ wf) {
  const int wid = blockIdx.x * 256 + threadIdx.x;   // 0..12799
  const int kind = wid >= 6400 ? 1 : 0;             // 0: W, 1: W^2 + sp
  const int fid = kind ? wid - 6400 : wid;
  const int ij = fid >> 8;                          // 0..24
  const int rest = fid & 255;
  const int n = rest >> 6, l = rest & 63;
  const int col = n * 16 + (l & 15);                // output channel k
  const int m0 = ij * 32 + (l >> 4) * 8;            // m row base
  const float sp = log1pf(expf(w_sigma[col]));
  unsigned short v[8];
#pragma unroll
  for (int i = 0; i < 8; ++i) {
    float wv = w_mu[(m0 + i) * 64 + col];
    float x = kind ? (wv * wv + sp) : wv;
    v[i] = f2bf(x);
  }
  uint4 pk;
  pk.x = v[0] | ((unsigned)v[1] << 16);
  pk.y = v[2] | ((unsigned)v[3] << 16);
  pk.z = v[4] | ((unsigned)v[5] << 16);
  pk.w = v[6] | ((unsigned)v[7] << 16);
  *(uint4*)(wf + (size_t)((ij * 8 + kind * 4 + n) * 64 + l) * 8) = pk;
}

// ---------------- fused: gemm (G, mu_out, dv) + stream Sigma_out slab ----------------
__global__ __launch_bounds__(256) void fused(
    const float* __restrict__ mu_in, const float* __restrict__ Sigma_in,
    const float* __restrict__ w_sigma, const unsigned short* __restrict__ wf,
    float* __restrict__ out) {
  __shared__ unsigned short mu_sh[196 * LDAP];
  __shared__ unsigned short sd_sh[196 * LDAP];
  __shared__ float g_sh[16][100];
  __shared__ float dv_sh[16][64];
  const int r = blockIdx.x;            // row tile 0..6 (rows 16r..16r+15)
  const int zh = blockIdx.y;           // 0: q in [0,64), 1: q in [64,100)
  const int b = blockIdx.z;
  const int t = threadIdx.x, l = t & 63, w = t >> 6;
  const int laneP = l & 15, g16 = (l >> 4) * 8;
  const bool hasDv = (zh == 0) ? (r <= 3) : (r >= 4);  // slab contains q==p?

  // ---- stage mu[b] (and diag Sigma[b]) as bf16, padded rows ----
  const float4* mu4 = (const float4*)(mu_in + (size_t)b * 6272);
  for (int f = t; f < 1568; f += 256) {
    const float4 v = mu4[f];
    const int row = f >> 3, c = (f & 7) * 4;
    ushort4 pv;
    pv.x = f2bf(v.x); pv.y = f2bf(v.y); pv.z = f2bf(v.z); pv.w = f2bf(v.w);
    *(ushort4*)(mu_sh + row * LDAP + c) = pv;
  }
  if (hasDv) {
    for (int f = t; f < 1568; f += 256) {
      const int n = f >> 3, c = (f & 7) * 4;
      const float4 v = *(const float4*)(Sigma_in +
          ((size_t)(b * 196 + n) * 196 + n) * 32 + c);
      ushort4 pv;
      pv.x = f2bf(v.x); pv.y = f2bf(v.y); pv.z = f2bf(v.z); pv.w = f2bf(v.w);
      *(ushort4*)(sd_sh + n * LDAP + c) = pv;
    }
  }
  __syncthreads();

  // ---- MFMA phase: per-wave roles ----
  const int gTile = (zh == 0) ? w : (w < 3 ? 4 + w : -1);
  const bool doMu = (zh == 1);
  const int nT = w;                                  // k-tile for mu/dv

  int pA = r * 16 + laneP; if (pA > 99) pA = 99;
  const int baseA = ((pA / 10) * 14 + (pA % 10)) * LDAP + g16;
  int gcol = 0, baseB = 0;
  if (gTile >= 0) {
    gcol = gTile * 16 + laneP;
    const int pc = gcol > 99 ? 99 : gcol;
    baseB = ((pc / 10) * 14 + (pc % 10)) * LDAP + g16;
  }
  f32x4 accG = {}, accM = {}, accD = {};
#pragma unroll
  for (int ij = 0; ij < 25; ++ij) {
    const int off = ((ij / 5) * 14 + (ij % 5)) * LDAP;
    const short8 fA = *(const short8*)(mu_sh + baseA + off);
    if (gTile >= 0) {
      const short8 fB = *(const short8*)(mu_sh + baseB + off);
      accG = __builtin_amdgcn_mfma_f32_16x16x32_bf16(fA, fB, accG, 0, 0, 0);
    }
    if (doMu) {
      const short8 bw = *(const short8*)(wf + (size_t)((ij * 8 + nT) * 64 + l) * 8);
      accM = __builtin_amdgcn_mfma_f32_16x16x32_bf16(fA, bw, accM, 0, 0, 0);
    }
    if (hasDv) {
      const short8 fS = *(const short8*)(sd_sh + baseA + off);
      const short8 b2 = *(const short8*)(wf + (size_t)((ij * 8 + 4 + nT) * 64 + l) * 8);
      accD = __builtin_amdgcn_mfma_f32_16x16x32_bf16(fS, b2, accD, 0, 0, 0);
    }
  }
  const int prow0 = (l >> 4) * 4;
  if (gTile >= 0 && gcol < 100) {
#pragma unroll
    for (int j = 0; j < 4; ++j) g_sh[prow0 + j][gcol] = accG[j];
  }
  if (doMu) {
    float* mo = out + (size_t)b * 6400;
    const int k = nT * 16 + laneP;
#pragma unroll
    for (int j = 0; j < 4; ++j) {
      const int p = r * 16 + prow0 + j;
      if (p < 100) mo[p * 64 + k] = accM[j];
    }
  }
  if (hasDv) {
    const int k = nT * 16 + laneP;
#pragma unroll
    for (int j = 0; j < 4; ++j) dv_sh[prow0 + j][k] = accD[j];
  }
  __syncthreads();

  // ---- write phase: stream this block's Sigma_out slab ----
  const int nrows = (r == 6) ? 4 : 16;
  const int koff = (t & 15) * 4;
  const float4 wsv = *(const float4*)(w_sigma + koff);
  float4 sp4;
  sp4.x = log1pf(expf(wsv.x));
  sp4.y = log1pf(expf(wsv.y));
  sp4.z = log1pf(expf(wsv.z));
  sp4.w = log1pf(expf(wsv.w));
  const int p0 = r * 16;
  float* sig = out + MU_OUT_SZ + ((size_t)(b * 100 + p0) * 100) * 64;

  if (zh == 0) {
    const int total = nrows << 10;                   // nrows * 64q * 16
    for (int l4 = t; l4 < total; l4 += 256) {
      const int prow = l4 >> 10, rem = l4 & 1023;
      const int q = rem >> 4;
      const float g = g_sh[prow][q];
      float4 v;
      v.x = sp4.x * g; v.y = sp4.y * g; v.z = sp4.z * g; v.w = sp4.w * g;
      if (q == p0 + prow) {
        const float4 dvv = *(const float4*)&dv_sh[prow][koff];
        v.x += dvv.x; v.y += dvv.y; v.z += dvv.z; v.w += dvv.w;
      }
      if (q == koff)     v.x = fabsf(v.x);
      if (q == koff + 1) v.y = fabsf(v.y);
      if (q == koff + 2) v.z = fabsf(v.z);
      if (q == koff + 3) v.w = fabsf(v.w);
      *(float4*)(sig + ((size_t)prow * 100 + q) * 64 + koff) = v;
    }
  } else {
    const int total = nrows * 576;                   // nrows * 36q * 16
    for (int l4 = t; l4 < total; l4 += 256) {
      const int prow = l4 / 576, rem = l4 - prow * 576;
      const int q = 64 + (rem >> 4);
      const float g = g_sh[prow][q];
      float4 v;
      v.x = sp4.x * g; v.y = sp4.y * g; v.z = sp4.z * g; v.w = sp4.w * g;
      if (q == p0 + prow) {
        const float4 dvv = *(const float4*)&dv_sh[prow][koff];
        v.x += dvv.x; v.y += dvv.y; v.z += dvv.z; v.w += dvv.w;
      }
      // q >= 64 > koff+3 (<=63): diagonal-abs never applies in this half
      *(float4*)(sig + ((size_t)prow * 100 + q) * 64 + koff) = v;
    }
  }
}

extern "C" void kernel_launch(void* const* d_in, const int* in_sizes, int n_in,
                              void* d_out, int out_size, void* d_ws, size_t ws_size,
                              hipStream_t stream) {
  const float* mu_in    = (const float*)d_in[0];
  const float* Sigma_in = (const float*)d_in[1];
  const float* w_mu     = (const float*)d_in[2];
  const float* w_sigma  = (const float*)d_in[3];
  float* out = (float*)d_out;
  unsigned short* wf = (unsigned short*)d_ws;   // 204800 B

  prepW<<<50, 256, 0, stream>>>(w_mu, w_sigma, wf);
  fused<<<dim3(7, 2, NB), 256, 0, stream>>>(mu_in, Sigma_in, w_sigma, wf, out);
}